// Round 1
// baseline (594.118 us; speedup 1.0000x reference)
//
#include <hip/hip_runtime.h>

typedef __attribute__((ext_vector_type(8))) short bf16x8;
typedef __attribute__((ext_vector_type(8))) unsigned short u16x8;
typedef __attribute__((ext_vector_type(4))) float f32x4;

#define DEVINL __device__ __forceinline__

constexpr int TB = 2;        // batch
constexpr int TT = 4096;     // seq len
constexpr int TD = 512;      // model dim
constexpr int TH = 8;        // heads
constexpr int THD = 64;      // head dim
constexpr int TM = TB * TT;  // 8192 flattened rows

// fp32 -> bf16 round-to-nearest-even (values are small/finite; no NaN path needed)
DEVINL unsigned short f2b(float f) {
  unsigned u = __builtin_bit_cast(unsigned, f);
  u += 0x7FFFu + ((u >> 16) & 1u);
  return (unsigned short)(u >> 16);
}

// ---------------------------------------------------------------------------
// GEMM: Y[M][512] = X[M][512] @ W[512][512]^T  (torch Linear, both row-major
// along K -> symmetric staging). FINAL=0: bf16 out to Yb. FINAL=1: fp32+bias.
// 128x128 tile, BK=64, 4 waves each 64x64 (4x4 frags of 16x16x32 bf16 MFMA).
// ---------------------------------------------------------------------------
template<int FINAL>
__global__ __launch_bounds__(256, 2)
void gemm_xwt(const float* __restrict__ X, const float* __restrict__ W,
              unsigned short* __restrict__ Yb, float* __restrict__ Yf,
              const float* __restrict__ bias)
{
  constexpr int K = TD, N = TD;
  // pitch 72 ushort = 144 B = 36 words == 4 mod 32 banks -> conflict-free b128
  __shared__ unsigned short As[128][72];
  __shared__ unsigned short Bs[128][72];

  const int t    = threadIdx.x;
  const int lane = t & 63, w = t >> 6;
  const int fr = lane & 15, fq = lane >> 4;
  const int wr = (w >> 1) * 64, wc = (w & 1) * 64;
  const int bm = blockIdx.x * 128, bn = blockIdx.y * 128;
  const int srow = t >> 1;         // staging row 0..127 (2 threads/row)
  const int skh  = (t & 1) * 32;   // k-half

  f32x4 acc[4][4];
  #pragma unroll
  for (int m = 0; m < 4; ++m)
    #pragma unroll
    for (int n = 0; n < 4; ++n)
      acc[m][n] = f32x4{0.f, 0.f, 0.f, 0.f};

  for (int k0 = 0; k0 < K; k0 += 64) {
    const float* srcA = X + (size_t)(bm + srow) * K + k0 + skh;
    const float* srcB = W + (size_t)(bn + srow) * K + k0 + skh;
    #pragma unroll
    for (int i = 0; i < 4; ++i) {
      float4 a0 = ((const float4*)srcA)[2 * i];
      float4 a1 = ((const float4*)srcA)[2 * i + 1];
      u16x8 oa = {f2b(a0.x), f2b(a0.y), f2b(a0.z), f2b(a0.w),
                  f2b(a1.x), f2b(a1.y), f2b(a1.z), f2b(a1.w)};
      *(u16x8*)&As[srow][skh + i * 8] = oa;
      float4 b0 = ((const float4*)srcB)[2 * i];
      float4 b1 = ((const float4*)srcB)[2 * i + 1];
      u16x8 ob = {f2b(b0.x), f2b(b0.y), f2b(b0.z), f2b(b0.w),
                  f2b(b1.x), f2b(b1.y), f2b(b1.z), f2b(b1.w)};
      *(u16x8*)&Bs[srow][skh + i * 8] = ob;
    }
    __syncthreads();
    #pragma unroll
    for (int kk = 0; kk < 2; ++kk) {
      bf16x8 af[4], bfv[4];
      #pragma unroll
      for (int m = 0; m < 4; ++m)
        af[m] = *(const bf16x8*)&As[wr + m * 16 + fr][kk * 32 + fq * 8];
      #pragma unroll
      for (int n = 0; n < 4; ++n)
        bfv[n] = *(const bf16x8*)&Bs[wc + n * 16 + fr][kk * 32 + fq * 8];
      #pragma unroll
      for (int m = 0; m < 4; ++m)
        #pragma unroll
        for (int n = 0; n < 4; ++n)
          acc[m][n] = __builtin_amdgcn_mfma_f32_16x16x32_bf16(af[m], bfv[n], acc[m][n], 0, 0, 0);
    }
    __syncthreads();
  }

  // C/D layout (m89-verified): col = lane&15, row = (lane>>4)*4 + reg
  #pragma unroll
  for (int m = 0; m < 4; ++m) {
    const int gm = bm + wr + m * 16 + fq * 4;
    #pragma unroll
    for (int n = 0; n < 4; ++n) {
      const int gn = bn + wc + n * 16 + fr;
      #pragma unroll
      for (int i = 0; i < 4; ++i) {
        float v = acc[m][n][i];
        if (FINAL) Yf[(size_t)(gm + i) * N + gn] = v + bias[gn];
        else       Yb[(size_t)(gm + i) * N + gn] = f2b(v);
      }
    }
  }
}

// ---------------------------------------------------------------------------
// Fused attention per (b,h,qblock): S = QK^T/8, softmax (no max-sub: |s|<~2),
// writes normalized attn (fp32) + accumulates Z = P V. Two-pass over KV:
// pass1 computes row denominators, pass2 recomputes exp, writes attn, does PV.
// 4 waves x 16 q-rows = QBLK 64. KV tiles (64) double-buffered, reg-prefetch.
// ---------------------------------------------------------------------------
__global__ __launch_bounds__(256, 2)
void attn_fused(const unsigned short* __restrict__ Qb,
                const unsigned short* __restrict__ Kb,
                const unsigned short* __restrict__ Vb,
                float* __restrict__ attnO, float* __restrict__ Z)
{
  __shared__ unsigned short Qs[64][72];        // 9.2 KB
  __shared__ unsigned short Ks[2][64][72];     // 18.4 KB   K rows [kv][d]
  __shared__ unsigned short VTs[2][64][72];    // 18.4 KB   V transposed [d][kv]
  __shared__ unsigned short Ps[4][16][72];     // 9.2 KB    per-wave P [q][kv]

  const int t    = threadIdx.x;
  const int lane = t & 63, w = t >> 6;
  const int fr = lane & 15, fq = lane >> 4;
  const int bh = blockIdx.y;            // 0..15 = b*8+h
  const int b  = bh >> 3, h = bh & 7;
  const int q0 = blockIdx.x * 64;

  const size_t rowQ  = ((size_t)(b * TT + q0)) * TD + h * THD;
  const size_t rowKV = ((size_t)(b * TT)) * TD + h * THD;

  const int tr = t >> 2;           // 0..63 staging row
  const int tc = (t & 3) * 16;     // 0,16,32,48

  auto loadT = [&](const unsigned short* base, int kv0, u16x8& r0, u16x8& r1) {
    const unsigned short* src = base + rowKV + (size_t)(kv0 + tr) * TD + tc;
    r0 = *(const u16x8*)src;
    r1 = *(const u16x8*)(src + 8);
  };
  auto writeK = [&](int buf, const u16x8& r0, const u16x8& r1) {
    *(u16x8*)&Ks[buf][tr][tc]     = r0;
    *(u16x8*)&Ks[buf][tr][tc + 8] = r1;
  };
  auto writeVT = [&](int buf, const u16x8& r0, const u16x8& r1) {
    #pragma unroll
    for (int i = 0; i < 8; ++i) VTs[buf][tc + i][tr] = r0[i];
    #pragma unroll
    for (int i = 0; i < 8; ++i) VTs[buf][tc + 8 + i][tr] = r1[i];
  };

  // stage Q block + first K tile
  {
    const unsigned short* src = Qb + rowQ + (size_t)tr * TD + tc;
    *(u16x8*)&Qs[tr][tc]     = *(const u16x8*)src;
    *(u16x8*)&Qs[tr][tc + 8] = *(const u16x8*)(src + 8);
  }
  u16x8 kr0, kr1, vr0, vr1;
  loadT(Kb, 0, kr0, kr1);
  writeK(0, kr0, kr1);
  __syncthreads();

  // Q fragments held in registers for the whole kernel (A-frag: row=lane&15)
  bf16x8 aq[2];
  aq[0] = *(const bf16x8*)&Qs[w * 16 + fr][fq * 8];
  aq[1] = *(const bf16x8*)&Qs[w * 16 + fr][32 + fq * 8];

  constexpr int NT = TT / 64;   // 64 kv tiles
  constexpr float SC = 0.125f;  // 1/sqrt(64)

  // ---- pass 1: row sums of exp(s/8) ----
  float lsum[4] = {0.f, 0.f, 0.f, 0.f};
  for (int j = 0; j < NT; ++j) {
    const int cur = j & 1;
    if (j + 1 < NT) loadT(Kb, (j + 1) * 64, kr0, kr1);
    #pragma unroll
    for (int n = 0; n < 4; ++n) {
      f32x4 s = f32x4{0.f, 0.f, 0.f, 0.f};
      #pragma unroll
      for (int kk = 0; kk < 2; ++kk) {
        bf16x8 bk = *(const bf16x8*)&Ks[cur][n * 16 + fr][kk * 32 + fq * 8];
        s = __builtin_amdgcn_mfma_f32_16x16x32_bf16(aq[kk], bk, s, 0, 0, 0);
      }
      #pragma unroll
      for (int i = 0; i < 4; ++i) lsum[i] += __expf(s[i] * SC);
    }
    if (j + 1 < NT) writeK(cur ^ 1, kr0, kr1);
    __syncthreads();
  }
  // reduce across the 16 lanes (fr) sharing the same row set (fq)
  #pragma unroll
  for (int msk = 1; msk <= 8; msk <<= 1)
    #pragma unroll
    for (int i = 0; i < 4; ++i) lsum[i] += __shfl_xor(lsum[i], msk, 64);
  float rinv[4];
  #pragma unroll
  for (int i = 0; i < 4; ++i) rinv[i] = 1.0f / lsum[i];

  // ---- pass 2: recompute, write attn, accumulate PV ----
  loadT(Kb, 0, kr0, kr1);
  loadT(Vb, 0, vr0, vr1);
  writeK(0, kr0, kr1);
  writeVT(0, vr0, vr1);
  __syncthreads();

  f32x4 accz[4];
  #pragma unroll
  for (int n = 0; n < 4; ++n) accz[n] = f32x4{0.f, 0.f, 0.f, 0.f};

  const size_t abase = ((size_t)bh * TT + q0 + w * 16 + fq * 4) * TT + fr;

  for (int j = 0; j < NT; ++j) {
    const int cur = j & 1;
    const int kv0 = j * 64;
    if (j + 1 < NT) {
      loadT(Kb, (j + 1) * 64, kr0, kr1);
      loadT(Vb, (j + 1) * 64, vr0, vr1);
    }
    #pragma unroll
    for (int n = 0; n < 4; ++n) {
      f32x4 s = f32x4{0.f, 0.f, 0.f, 0.f};
      #pragma unroll
      for (int kk = 0; kk < 2; ++kk) {
        bf16x8 bk = *(const bf16x8*)&Ks[cur][n * 16 + fr][kk * 32 + fq * 8];
        s = __builtin_amdgcn_mfma_f32_16x16x32_bf16(aq[kk], bk, s, 0, 0, 0);
      }
      #pragma unroll
      for (int i = 0; i < 4; ++i) {
        float p = __expf(s[i] * SC) * rinv[i];
        attnO[abase + (size_t)i * TT + kv0 + n * 16] = p;   // fp32 normalized
        Ps[w][fq * 4 + i][n * 16 + fr] = f2b(p);            // bf16 for PV
      }
    }
    // ensure this wave's Ps writes landed before reading A-fragments of P
    asm volatile("s_waitcnt lgkmcnt(0)" ::: "memory");
    __builtin_amdgcn_sched_barrier(0);
    #pragma unroll
    for (int kk = 0; kk < 2; ++kk) {
      bf16x8 ap = *(const bf16x8*)&Ps[w][fr][kk * 32 + fq * 8];
      #pragma unroll
      for (int n = 0; n < 4; ++n) {
        bf16x8 bv = *(const bf16x8*)&VTs[cur][n * 16 + fr][kk * 32 + fq * 8];
        accz[n] = __builtin_amdgcn_mfma_f32_16x16x32_bf16(ap, bv, accz[n], 0, 0, 0);
      }
    }
    if (j + 1 < NT) {
      writeK(cur ^ 1, kr0, kr1);
      writeVT(cur ^ 1, vr0, vr1);
    }
    __syncthreads();
  }

  // Z in [B*T, D] layout (head-transpose folded into addressing), fp32
  const size_t zbase = ((size_t)(b * TT + q0 + w * 16 + fq * 4)) * TD + h * THD + fr;
  #pragma unroll
  for (int n = 0; n < 4; ++n)
    #pragma unroll
    for (int i = 0; i < 4; ++i)
      Z[zbase + (size_t)i * TD + n * 16] = accz[n][i];
}

// ---------------------------------------------------------------------------
extern "C" void kernel_launch(void* const* d_in, const int* in_sizes, int n_in,
                              void* d_out, int out_size, void* d_ws, size_t ws_size,
                              hipStream_t stream) {
  const float* queries = (const float*)d_in[0];
  const float* keys    = (const float*)d_in[1];
  const float* values  = (const float*)d_in[2];
  const float* Wq = (const float*)d_in[3];
  const float* Wk = (const float*)d_in[4];
  const float* Wv = (const float*)d_in[5];
  const float* Wo = (const float*)d_in[6];
  const float* bo = (const float*)d_in[7];

  float* out  = (float*)d_out;                       // [2,4096,512]
  float* attn = out + (size_t)TM * TD;               // [2,8,4096,4096]

  // workspace: Q/K/V projected bf16 (8.4 MB each) + Z fp32 (16.8 MB) = 42 MB
  unsigned short* qb = (unsigned short*)d_ws;
  unsigned short* kb = qb + (size_t)TM * TD;
  unsigned short* vb = kb + (size_t)TM * TD;
  float*          zf = (float*)(vb + (size_t)TM * TD);

  dim3 gg(TM / 128, TD / 128), bb(256);
  gemm_xwt<0><<<gg, bb, 0, stream>>>(queries, Wq, qb, nullptr, nullptr);
  gemm_xwt<0><<<gg, bb, 0, stream>>>(keys,    Wk, kb, nullptr, nullptr);
  gemm_xwt<0><<<gg, bb, 0, stream>>>(values,  Wv, vb, nullptr, nullptr);

  attn_fused<<<dim3(TT / 64, TB * TH), bb, 0, stream>>>(qb, kb, vb, attn, zf);

  gemm_xwt<1><<<gg, bb, 0, stream>>>(zf, Wo, nullptr, out, bo);
}

// Round 2
// 545.353 us; speedup vs baseline: 1.0894x; 1.0894x over previous
//
#include <hip/hip_runtime.h>

typedef __attribute__((ext_vector_type(8))) short bf16x8;
typedef __attribute__((ext_vector_type(8))) unsigned short u16x8;
typedef __attribute__((ext_vector_type(4))) float f32x4;

#define DEVINL __device__ __forceinline__

constexpr int TB = 2;        // batch
constexpr int TT = 4096;     // seq len
constexpr int TD = 512;      // model dim
constexpr int TH = 8;        // heads
constexpr int THD = 64;      // head dim
constexpr int TM = TB * TT;  // 8192 flattened rows

// fp32 -> bf16 round-to-nearest-even (values are small/finite; no NaN path needed)
DEVINL unsigned short f2b(float f) {
  unsigned u = __builtin_bit_cast(unsigned, f);
  u += 0x7FFFu + ((u >> 16) & 1u);
  return (unsigned short)(u >> 16);
}

// barrier that only waits LDS ops (global stores may stay in flight)
DEVINL void lgkm_barrier() {
  asm volatile("s_waitcnt lgkmcnt(0)" ::: "memory");
  __builtin_amdgcn_s_barrier();
  __builtin_amdgcn_sched_barrier(0);
}

// ---------------------------------------------------------------------------
// GEMM: Y = X[M][512] @ W[512][512]^T  (torch Linear; both row-major along K).
// MODE 0: bf16 out, row-major Y[m][n].
// MODE 1: fp32 out + bias, row-major.
// MODE 2: bf16 out, per-head TRANSPOSED: VT[b][h][d][T]  (n=h*64+d, m=b*T+t).
//         Done by swapping mfma operands (A/B frags share the same lane map),
//         so D = Y^T lands with t contiguous in lanes -> coalesced-ish stores.
// 128x128 tile, BK=64, 4 waves each 64x64 (4x4 frags of 16x16x32 bf16 MFMA).
// ---------------------------------------------------------------------------
template<int MODE>
__global__ __launch_bounds__(256, 2)
void gemm_xwt(const float* __restrict__ X, const float* __restrict__ W,
              unsigned short* __restrict__ Yb, float* __restrict__ Yf,
              const float* __restrict__ bias)
{
  constexpr int K = TD, N = TD;
  // pitch 72 ushort = 36 words == 4 mod 32 banks -> conflict-free b128
  __shared__ unsigned short As[128][72];
  __shared__ unsigned short Bs[128][72];

  const int t    = threadIdx.x;
  const int lane = t & 63, w = t >> 6;
  const int fr = lane & 15, fq = lane >> 4;
  const int wr = (w >> 1) * 64, wc = (w & 1) * 64;
  const int bm = blockIdx.x * 128, bn = blockIdx.y * 128;
  const int srow = t >> 1;         // staging row 0..127 (2 threads/row)
  const int skh  = (t & 1) * 32;   // k-half

  f32x4 acc[4][4];
  #pragma unroll
  for (int i = 0; i < 4; ++i)
    #pragma unroll
    for (int j = 0; j < 4; ++j)
      acc[i][j] = f32x4{0.f, 0.f, 0.f, 0.f};

  for (int k0 = 0; k0 < K; k0 += 64) {
    const float* srcA = X + (size_t)(bm + srow) * K + k0 + skh;
    const float* srcB = W + (size_t)(bn + srow) * K + k0 + skh;
    #pragma unroll
    for (int i = 0; i < 4; ++i) {
      float4 a0 = ((const float4*)srcA)[2 * i];
      float4 a1 = ((const float4*)srcA)[2 * i + 1];
      u16x8 oa = {f2b(a0.x), f2b(a0.y), f2b(a0.z), f2b(a0.w),
                  f2b(a1.x), f2b(a1.y), f2b(a1.z), f2b(a1.w)};
      *(u16x8*)&As[srow][skh + i * 8] = oa;
      float4 b0 = ((const float4*)srcB)[2 * i];
      float4 b1 = ((const float4*)srcB)[2 * i + 1];
      u16x8 ob = {f2b(b0.x), f2b(b0.y), f2b(b0.z), f2b(b0.w),
                  f2b(b1.x), f2b(b1.y), f2b(b1.z), f2b(b1.w)};
      *(u16x8*)&Bs[srow][skh + i * 8] = ob;
    }
    __syncthreads();
    #pragma unroll
    for (int kk = 0; kk < 2; ++kk) {
      bf16x8 af[4], bfv[4];
      #pragma unroll
      for (int i = 0; i < 4; ++i)
        af[i] = *(const bf16x8*)&As[wr + i * 16 + fr][kk * 32 + fq * 8];
      #pragma unroll
      for (int j = 0; j < 4; ++j)
        bfv[j] = *(const bf16x8*)&Bs[wc + j * 16 + fr][kk * 32 + fq * 8];
      #pragma unroll
      for (int i = 0; i < 4; ++i)
        #pragma unroll
        for (int j = 0; j < 4; ++j) {
          if (MODE == 2)
            acc[i][j] = __builtin_amdgcn_mfma_f32_16x16x32_bf16(bfv[i], af[j], acc[i][j], 0, 0, 0);
          else
            acc[i][j] = __builtin_amdgcn_mfma_f32_16x16x32_bf16(af[i], bfv[j], acc[i][j], 0, 0, 0);
        }
    }
    __syncthreads();
  }

  // C/D layout (m89-verified): col = lane&15, row = (lane>>4)*4 + reg
  #pragma unroll
  for (int i = 0; i < 4; ++i) {
    #pragma unroll
    for (int j = 0; j < 4; ++j) {
      #pragma unroll
      for (int ii = 0; ii < 4; ++ii) {
        float v = acc[i][j][ii];
        if (MODE == 2) {
          // D rows = N-dim (from Bs), D cols = M-dim (from As)
          const int Nidx = bn + wc + i * 16 + fq * 4 + ii;
          const int Midx = bm + wr + j * 16 + fr;
          const int h = Nidx >> 6, d = Nidx & (THD - 1);
          const int b = Midx >> 12, tt = Midx & (TT - 1);
          Yb[((size_t)(b * TH + h) * THD + d) * TT + tt] = f2b(v);
        } else {
          const int gm = bm + wr + i * 16 + fq * 4 + ii;
          const int gn = bn + wc + j * 16 + fr;
          if (MODE == 1) Yf[(size_t)gm * N + gn] = v + bias[gn];
          else           Yb[(size_t)gm * N + gn] = f2b(v);
        }
      }
    }
  }
}

// ---------------------------------------------------------------------------
// Fused attention per (b,h,qblock): S = QK^T/8, softmax (no max-sub: |s|<~2),
// writes normalized attn (fp32, nontemporal) + accumulates Z = P V.
// Pass1: row denominators. Pass2: recompute, write attn, PV.
// V comes in pre-transposed per head: VT[b][h][d][T] -> vectorized staging.
// Barriers wait lgkm only: attn stores pipeline across tiles.
// ---------------------------------------------------------------------------
__global__ __launch_bounds__(256, 2)
void attn_fused(const unsigned short* __restrict__ Qb,
                const unsigned short* __restrict__ Kb,
                const unsigned short* __restrict__ VTg,
                float* __restrict__ attnO, float* __restrict__ Z)
{
  __shared__ unsigned short Qs[64][72];        // 9.2 KB
  __shared__ unsigned short Ks[2][64][72];     // 18.4 KB  K rows [kv][d]
  __shared__ unsigned short VTs[2][64][72];    // 18.4 KB  V^T rows [d][kv]
  __shared__ unsigned short Ps[4][16][72];     // 9.2 KB   per-wave P [q][kv]

  const int t    = threadIdx.x;
  const int lane = t & 63, w = t >> 6;
  const int fr = lane & 15, fq = lane >> 4;
  const int bh = blockIdx.y;            // 0..15 = b*8+h
  const int b  = bh >> 3, h = bh & 7;
  const int q0 = blockIdx.x * 64;

  const size_t rowQ  = ((size_t)(b * TT + q0)) * TD + h * THD;
  const size_t rowKV = ((size_t)(b * TT)) * TD + h * THD;
  const size_t vtBase = (size_t)bh * THD * TT;   // VT[b][h][0][0]

  const int tr = t >> 2;           // 0..63 staging row
  const int tc = (t & 3) * 16;     // 0,16,32,48

  auto loadK = [&](int kv0, u16x8& r0, u16x8& r1) {
    const unsigned short* src = Kb + rowKV + (size_t)(kv0 + tr) * TD + tc;
    r0 = *(const u16x8*)src;
    r1 = *(const u16x8*)(src + 8);
  };
  auto loadVT = [&](int kv0, u16x8& r0, u16x8& r1) {
    const unsigned short* src = VTg + vtBase + (size_t)tr * TT + kv0 + tc;
    r0 = *(const u16x8*)src;
    r1 = *(const u16x8*)(src + 8);
  };
  auto writeK = [&](int buf, const u16x8& r0, const u16x8& r1) {
    *(u16x8*)&Ks[buf][tr][tc]     = r0;
    *(u16x8*)&Ks[buf][tr][tc + 8] = r1;
  };
  auto writeVT = [&](int buf, const u16x8& r0, const u16x8& r1) {
    *(u16x8*)&VTs[buf][tr][tc]     = r0;
    *(u16x8*)&VTs[buf][tr][tc + 8] = r1;
  };

  // stage Q block + first K tile
  {
    const unsigned short* src = Qb + rowQ + (size_t)tr * TD + tc;
    *(u16x8*)&Qs[tr][tc]     = *(const u16x8*)src;
    *(u16x8*)&Qs[tr][tc + 8] = *(const u16x8*)(src + 8);
  }
  u16x8 kr0, kr1, vr0, vr1;
  loadK(0, kr0, kr1);
  writeK(0, kr0, kr1);
  lgkm_barrier();

  // Q fragments held in registers (A-frag: row=lane&15, k-group by lane>>4)
  bf16x8 aq[2];
  aq[0] = *(const bf16x8*)&Qs[w * 16 + fr][fq * 8];
  aq[1] = *(const bf16x8*)&Qs[w * 16 + fr][32 + fq * 8];

  constexpr int NT = TT / 64;   // 64 kv tiles
  constexpr float SC = 0.125f;  // 1/sqrt(64)

  // ---- pass 1: row sums of exp(s/8) ----
  float lsum[4] = {0.f, 0.f, 0.f, 0.f};
  for (int j = 0; j < NT; ++j) {
    const int cur = j & 1;
    if (j + 1 < NT) loadK((j + 1) * 64, kr0, kr1);
    #pragma unroll
    for (int n = 0; n < 4; ++n) {
      f32x4 s = f32x4{0.f, 0.f, 0.f, 0.f};
      #pragma unroll
      for (int kk = 0; kk < 2; ++kk) {
        bf16x8 bk = *(const bf16x8*)&Ks[cur][n * 16 + fr][kk * 32 + fq * 8];
        s = __builtin_amdgcn_mfma_f32_16x16x32_bf16(aq[kk], bk, s, 0, 0, 0);
      }
      #pragma unroll
      for (int i = 0; i < 4; ++i) lsum[i] += __expf(s[i] * SC);
    }
    if (j + 1 < NT) writeK(cur ^ 1, kr0, kr1);
    lgkm_barrier();
  }
  // reduce across the 16 lanes (fr) sharing the same rows (fq group)
  #pragma unroll
  for (int msk = 1; msk <= 8; msk <<= 1)
    #pragma unroll
    for (int i = 0; i < 4; ++i) lsum[i] += __shfl_xor(lsum[i], msk, 64);
  float rinv[4];
  #pragma unroll
  for (int i = 0; i < 4; ++i) rinv[i] = 1.0f / lsum[i];

  // ---- pass 2: recompute, write attn, accumulate PV ----
  loadK(0, kr0, kr1);
  loadVT(0, vr0, vr1);
  writeK(0, kr0, kr1);
  writeVT(0, vr0, vr1);
  lgkm_barrier();

  f32x4 accz[4];
  #pragma unroll
  for (int n = 0; n < 4; ++n) accz[n] = f32x4{0.f, 0.f, 0.f, 0.f};

  const size_t abase = ((size_t)bh * TT + q0 + w * 16 + fq * 4) * TT + fr;

  for (int j = 0; j < NT; ++j) {
    const int cur = j & 1;
    const int kv0 = j * 64;
    if (j + 1 < NT) {
      loadK((j + 1) * 64, kr0, kr1);
      loadVT((j + 1) * 64, vr0, vr1);
    }
    #pragma unroll
    for (int n = 0; n < 4; ++n) {
      f32x4 s = f32x4{0.f, 0.f, 0.f, 0.f};
      #pragma unroll
      for (int kk = 0; kk < 2; ++kk) {
        bf16x8 bk = *(const bf16x8*)&Ks[cur][n * 16 + fr][kk * 32 + fq * 8];
        s = __builtin_amdgcn_mfma_f32_16x16x32_bf16(aq[kk], bk, s, 0, 0, 0);
      }
      #pragma unroll
      for (int i = 0; i < 4; ++i) {
        float p = __expf(s[i] * SC) * rinv[i];
        __builtin_nontemporal_store(p, &attnO[abase + (size_t)i * TT + kv0 + n * 16]);
        Ps[w][fq * 4 + i][n * 16 + fr] = f2b(p);            // bf16 for PV
      }
    }
    // this wave's Ps writes must land before reading P as A-fragments
    asm volatile("s_waitcnt lgkmcnt(0)" ::: "memory");
    __builtin_amdgcn_sched_barrier(0);
    #pragma unroll
    for (int kk = 0; kk < 2; ++kk) {
      bf16x8 ap = *(const bf16x8*)&Ps[w][fr][kk * 32 + fq * 8];
      #pragma unroll
      for (int n = 0; n < 4; ++n) {
        bf16x8 bv = *(const bf16x8*)&VTs[cur][n * 16 + fr][kk * 32 + fq * 8];
        accz[n] = __builtin_amdgcn_mfma_f32_16x16x32_bf16(ap, bv, accz[n], 0, 0, 0);
      }
    }
    if (j + 1 < NT) {
      writeK(cur ^ 1, kr0, kr1);
      writeVT(cur ^ 1, vr0, vr1);
    }
    lgkm_barrier();
  }

  // Z in [B*T, D] layout (head-transpose folded into addressing), fp32
  const size_t zbase = ((size_t)(b * TT + q0 + w * 16 + fq * 4)) * TD + h * THD + fr;
  #pragma unroll
  for (int n = 0; n < 4; ++n)
    #pragma unroll
    for (int i = 0; i < 4; ++i)
      Z[zbase + (size_t)i * TD + n * 16] = accz[n][i];
}

// ---------------------------------------------------------------------------
extern "C" void kernel_launch(void* const* d_in, const int* in_sizes, int n_in,
                              void* d_out, int out_size, void* d_ws, size_t ws_size,
                              hipStream_t stream) {
  const float* queries = (const float*)d_in[0];
  const float* keys    = (const float*)d_in[1];
  const float* values  = (const float*)d_in[2];
  const float* Wq = (const float*)d_in[3];
  const float* Wk = (const float*)d_in[4];
  const float* Wv = (const float*)d_in[5];
  const float* Wo = (const float*)d_in[6];
  const float* bo = (const float*)d_in[7];

  float* out  = (float*)d_out;                       // [2,4096,512]
  float* attn = out + (size_t)TM * TD;               // [2,8,4096,4096]

  // workspace: Q/K bf16 row-major, VT bf16 per-head transposed, Z fp32
  unsigned short* qb = (unsigned short*)d_ws;
  unsigned short* kb = qb + (size_t)TM * TD;
  unsigned short* vt = kb + (size_t)TM * TD;
  float*          zf = (float*)(vt + (size_t)TM * TD);

  dim3 gg(TM / 128, TD / 128), bb(256);
  gemm_xwt<0><<<gg, bb, 0, stream>>>(queries, Wq, qb, nullptr, nullptr);
  gemm_xwt<0><<<gg, bb, 0, stream>>>(keys,    Wk, kb, nullptr, nullptr);
  gemm_xwt<2><<<gg, bb, 0, stream>>>(values,  Wv, vt, nullptr, nullptr);

  attn_fused<<<dim3(TT / 64, TB * TH), bb, 0, stream>>>(qb, kb, vt, attn, zf);

  gemm_xwt<1><<<gg, bb, 0, stream>>>(zf, Wo, nullptr, out, bo);
}